// Round 1
// baseline (4367.247 us; speedup 1.0000x reference)
//
#include <hip/hip_runtime.h>
#include <hip/hip_bf16.h>
#include <math.h>

#define S_LEN 4096
#define HID   2048
#define NH    8
#define NVH   16
#define DK    128
#define DV    128
#define KEY_DIM  (NH*DK)    // 1024
#define VAL_DIM  (NVH*DV)   // 2048
#define SCALE_Q  0.08838834764831845f  // 128^-0.5

// ---------------------------------------------------------------------------
// Generic fp32 GEMM: C[M,N] = A[M,K] @ B[N,K]^T.  M % 64 == 0, K % 16 == 0,
// N arbitrary (guarded). 64x64 tile, 256 threads, 4x4 per thread.
// ---------------------------------------------------------------------------
__global__ __launch_bounds__(256) void gemm_bt(
    const float* __restrict__ A, const float* __restrict__ B,
    float* __restrict__ C, int M, int N, int K) {
  __shared__ float As[16][68];   // +4 pad keeps float4 alignment (68*4=272, %16==0)
  __shared__ float Bs[16][68];
  const int bm = blockIdx.y, bn = blockIdx.x;
  const int t = threadIdx.x;
  const int tx = t & 15, ty = t >> 4;
  const int lrow = t >> 2;            // 0..63
  const int lk0  = (t & 3) * 4;       // 0,4,8,12
  const int arow = bm * 64 + lrow;
  const int brow = bn * 64 + lrow;
  const bool bvalid = brow < N;

  float acc[4][4];
  #pragma unroll
  for (int i = 0; i < 4; i++)
    #pragma unroll
    for (int j = 0; j < 4; j++) acc[i][j] = 0.f;

  for (int k0 = 0; k0 < K; k0 += 16) {
    float4 av = *(const float4*)&A[(size_t)arow * K + k0 + lk0];
    float4 bv = bvalid ? *(const float4*)&B[(size_t)brow * K + k0 + lk0]
                       : make_float4(0.f, 0.f, 0.f, 0.f);
    As[lk0+0][lrow] = av.x; As[lk0+1][lrow] = av.y;
    As[lk0+2][lrow] = av.z; As[lk0+3][lrow] = av.w;
    Bs[lk0+0][lrow] = bv.x; Bs[lk0+1][lrow] = bv.y;
    Bs[lk0+2][lrow] = bv.z; Bs[lk0+3][lrow] = bv.w;
    __syncthreads();
    #pragma unroll
    for (int kk = 0; kk < 16; kk++) {
      float4 a = *(const float4*)&As[kk][ty * 4];
      float4 b = *(const float4*)&Bs[kk][tx * 4];
      float ar[4] = {a.x, a.y, a.z, a.w};
      float br[4] = {b.x, b.y, b.z, b.w};
      #pragma unroll
      for (int i = 0; i < 4; i++)
        #pragma unroll
        for (int j = 0; j < 4; j++) acc[i][j] += ar[i] * br[j];
    }
    __syncthreads();
  }
  #pragma unroll
  for (int i = 0; i < 4; i++) {
    int r = bm * 64 + ty * 4 + i;
    #pragma unroll
    for (int j = 0; j < 4; j++) {
      int c = bn * 64 + tx * 4 + j;
      if (c < N) C[(size_t)r * N + c] = acc[i][j];
    }
  }
}

// ---------------------------------------------------------------------------
// Causal depthwise conv (K=4) + SiLU + per-head l2norm (+scale) for q/k.
// pre: [S, KEY_DIM], cw: [KEY_DIM, 4], out: [S, NH, DK]
// grid (S, NH), 128 threads
// ---------------------------------------------------------------------------
__global__ __launch_bounds__(128) void conv_qk_kernel(
    const float* __restrict__ pre, const float* __restrict__ cw,
    float* __restrict__ out, float scale) {
  const int s = blockIdx.x, h = blockIdx.y, t = threadIdx.x;
  const int c = h * 128 + t;
  const float4 w = *(const float4*)&cw[c * 4];
  float y = pre[(size_t)s * KEY_DIM + c] * w.w;
  if (s >= 1) y += pre[(size_t)(s-1) * KEY_DIM + c] * w.z;
  if (s >= 2) y += pre[(size_t)(s-2) * KEY_DIM + c] * w.y;
  if (s >= 3) y += pre[(size_t)(s-3) * KEY_DIM + c] * w.x;
  float v = y / (1.f + expf(-y));   // silu
  float ss = v * v;
  #pragma unroll
  for (int off = 1; off < 64; off <<= 1) ss += __shfl_xor(ss, off, 64);
  __shared__ float red[2];
  if ((t & 63) == 0) red[t >> 6] = ss;
  __syncthreads();
  float inv = scale / sqrtf(red[0] + red[1] + 1e-6f);
  out[((size_t)s * NH + h) * 128 + t] = v * inv;
}

// ---------------------------------------------------------------------------
// Causal depthwise conv + SiLU for v. pre/out: [S, VAL_DIM]
// ---------------------------------------------------------------------------
__global__ __launch_bounds__(256) void conv_v_kernel(
    const float* __restrict__ pre, const float* __restrict__ cw,
    float* __restrict__ out) {
  const int id = blockIdx.x * 256 + threadIdx.x;   // S*VAL_DIM
  const int s = id >> 11, c = id & 2047;
  const float4 w = *(const float4*)&cw[c * 4];
  float y = pre[id] * w.w;
  if (s >= 1) y += pre[id - VAL_DIM]     * w.z;
  if (s >= 2) y += pre[id - 2*VAL_DIM]   * w.y;
  if (s >= 3) y += pre[id - 3*VAL_DIM]   * w.x;
  out[id] = y / (1.f + expf(-y));
}

// ---------------------------------------------------------------------------
// g = -exp(A_log)*softplus(a+dt_bias), beta = sigmoid(b).  [S, NVH]
// ---------------------------------------------------------------------------
__global__ __launch_bounds__(256) void gb_kernel(
    const float* __restrict__ a_pre, const float* __restrict__ b_pre,
    const float* __restrict__ A_log, const float* __restrict__ dt_bias,
    float* __restrict__ gv, float* __restrict__ bv) {
  const int id = blockIdx.x * 256 + threadIdx.x;  // S*NVH
  const int h = id & 15;
  float av = a_pre[id] + dt_bias[h];
  float sp = av > 20.f ? av : log1pf(expf(av));
  gv[id] = -expf(A_log[h]) * sp;
  bv[id] = 1.f / (1.f + expf(-b_pre[id]));
}

// ---------------------------------------------------------------------------
// Sequential delta-rule scan. 64 blocks = 16 heads x 4 col-blocks (32 cols).
// 256 threads: lane owns S[k0..k0+15][col] (16 regs). In-wave reductions.
// qn/kn: [S, NH, DK] (normalized), vc: [S, NVH, DV], o: [S, NVH, DV]
// ---------------------------------------------------------------------------
#define CH 32
__global__ __launch_bounds__(256) void scan_kernel(
    const float* __restrict__ qn, const float* __restrict__ kn,
    const float* __restrict__ vc, const float* __restrict__ gv,
    const float* __restrict__ bv, float* __restrict__ o) {
  const int head = blockIdx.x >> 2;
  const int cb   = blockIdx.x & 3;
  const int sh   = head >> 1;          // source q/k head (GVA=2)
  const int t = threadIdx.x;
  const int lane = t & 63, wave = t >> 6;
  const int coll = wave * 8 + (lane & 7);   // 0..31 within block
  const int kc = lane >> 3;                 // 0..7
  const int k0 = kc * 16;

  __shared__ float lk[CH][128];
  __shared__ float lq[CH][128];
  __shared__ float lv[CH][32];
  __shared__ float lg[CH];
  __shared__ float lb[CH];

  float S[16];
  #pragma unroll
  for (int i = 0; i < 16; i++) S[i] = 0.f;

  for (int s0 = 0; s0 < S_LEN; s0 += CH) {
    // stage chunk to LDS
    {
      const int c4 = t & 31, st0 = t >> 5;
      #pragma unroll
      for (int r = 0; r < 4; r++) {
        int ss = st0 + r * 8;
        size_t g = (size_t)(s0 + ss) * KEY_DIM + sh * 128 + c4 * 4;
        *(float4*)&lk[ss][c4 * 4] = *(const float4*)&kn[g];
        *(float4*)&lq[ss][c4 * 4] = *(const float4*)&qn[g];
      }
      const int c4v = t & 7, sv = t >> 3;
      *(float4*)&lv[sv][c4v * 4] =
          *(const float4*)&vc[(size_t)(s0 + sv) * VAL_DIM + head * 128 + cb * 32 + c4v * 4];
      if (t < CH)            lg[t]      = gv[(s0 + t) * NVH + head];
      else if (t < 2 * CH)   lb[t - CH] = bv[(s0 + t - CH) * NVH + head];
    }
    __syncthreads();

    for (int st = 0; st < CH; st++) {
      float eg = expf(lg[st]);
      float kkr[16], qqr[16];
      #pragma unroll
      for (int r = 0; r < 4; r++) {
        *(float4*)&kkr[r * 4] = *(const float4*)&lk[st][k0 + r * 4];
        *(float4*)&qqr[r * 4] = *(const float4*)&lq[st][k0 + r * 4];
      }
      float vvv = lv[st][coll];
      float bb  = lb[st];
      float p = 0.f;
      #pragma unroll
      for (int i = 0; i < 16; i++) S[i] *= eg;
      #pragma unroll
      for (int i = 0; i < 16; i++) p += kkr[i] * S[i];
      p += __shfl_xor(p, 8, 64);
      p += __shfl_xor(p, 16, 64);
      p += __shfl_xor(p, 32, 64);
      float delta = (vvv - p) * bb;
      float oo = 0.f;
      #pragma unroll
      for (int i = 0; i < 16; i++) { S[i] += kkr[i] * delta; oo += qqr[i] * S[i]; }
      oo += __shfl_xor(oo, 8, 64);
      oo += __shfl_xor(oo, 16, 64);
      oo += __shfl_xor(oo, 32, 64);
      if (kc == 0)
        o[(size_t)(s0 + st) * VAL_DIM + head * 128 + cb * 32 + coll] = oo;
    }
    __syncthreads();
  }
}

// ---------------------------------------------------------------------------
// Gated RMSNorm: og = o*silu(gate); og *= rsqrt(mean(og^2)+eps)*w_norm
// grid (S, NVH), 128 threads
// ---------------------------------------------------------------------------
__global__ __launch_bounds__(128) void norm_kernel(
    const float* __restrict__ o, const float* __restrict__ gate,
    const float* __restrict__ w_norm, float* __restrict__ og) {
  const int s = blockIdx.x, h = blockIdx.y, t = threadIdx.x;
  const size_t idx = (size_t)s * VAL_DIM + h * 128 + t;
  float gt = gate[idx];
  float val = o[idx] * (gt / (1.f + expf(-gt)));
  float ss = val * val;
  #pragma unroll
  for (int off = 1; off < 64; off <<= 1) ss += __shfl_xor(ss, off, 64);
  __shared__ float red[2];
  if ((t & 63) == 0) red[t >> 6] = ss;
  __syncthreads();
  float ms = (red[0] + red[1]) * (1.f / 128.f);
  og[idx] = val * (1.f / sqrtf(ms + 1e-6f)) * w_norm[t];
}

// ---------------------------------------------------------------------------
extern "C" void kernel_launch(void* const* d_in, const int* in_sizes, int n_in,
                              void* d_out, int out_size, void* d_ws, size_t ws_size,
                              hipStream_t stream) {
  const float* x       = (const float*)d_in[0];
  const float* Wq      = (const float*)d_in[1];
  const float* Wk      = (const float*)d_in[2];
  const float* Wv      = (const float*)d_in[3];
  const float* Wa      = (const float*)d_in[4];
  const float* Wb      = (const float*)d_in[5];
  const float* Wg      = (const float*)d_in[6];
  const float* Wo      = (const float*)d_in[7];
  const float* conv_q  = (const float*)d_in[8];
  const float* conv_k  = (const float*)d_in[9];
  const float* conv_v  = (const float*)d_in[10];
  const float* A_log   = (const float*)d_in[11];
  const float* dt_bias = (const float*)d_in[12];
  const float* w_norm  = (const float*)d_in[13];
  float* out = (float*)d_out;

  float* W = (float*)d_ws;
  float* q_pre = W;                                   // 4096*1024
  float* k_pre = q_pre + (size_t)S_LEN * KEY_DIM;     // 4096*1024
  float* v_pre = k_pre + (size_t)S_LEN * KEY_DIM;     // 4096*2048
  float* qn    = v_pre + (size_t)S_LEN * VAL_DIM;     // 4096*1024
  float* kn    = qn    + (size_t)S_LEN * KEY_DIM;     // 4096*1024
  float* vcb   = kn    + (size_t)S_LEN * KEY_DIM;     // 4096*2048
  float* a_pre = vcb   + (size_t)S_LEN * VAL_DIM;     // 4096*16
  float* b_pre = a_pre + (size_t)S_LEN * NVH;
  float* gv    = b_pre + (size_t)S_LEN * NVH;
  float* bv    = gv    + (size_t)S_LEN * NVH;
  // reuse: gate occupies q_pre..k_pre (8.4M floats), o -> v_pre, og -> vcb
  float* gate  = q_pre;
  float* obuf  = v_pre;
  float* ogbuf = vcb;

  // 1) projections
  gemm_bt<<<dim3(KEY_DIM/64, S_LEN/64), 256, 0, stream>>>(x, Wq, q_pre, S_LEN, KEY_DIM, HID);
  gemm_bt<<<dim3(KEY_DIM/64, S_LEN/64), 256, 0, stream>>>(x, Wk, k_pre, S_LEN, KEY_DIM, HID);
  gemm_bt<<<dim3(VAL_DIM/64, S_LEN/64), 256, 0, stream>>>(x, Wv, v_pre, S_LEN, VAL_DIM, HID);
  gemm_bt<<<dim3(1, S_LEN/64), 256, 0, stream>>>(x, Wa, a_pre, S_LEN, NVH, HID);
  gemm_bt<<<dim3(1, S_LEN/64), 256, 0, stream>>>(x, Wb, b_pre, S_LEN, NVH, HID);

  // 2) conv + silu (+ l2norm for q/k), gating scalars
  conv_qk_kernel<<<dim3(S_LEN, NH), 128, 0, stream>>>(q_pre, conv_q, qn, SCALE_Q);
  conv_qk_kernel<<<dim3(S_LEN, NH), 128, 0, stream>>>(k_pre, conv_k, kn, 1.f);
  conv_v_kernel<<<(S_LEN*VAL_DIM)/256, 256, 0, stream>>>(v_pre, conv_v, vcb);
  gb_kernel<<<(S_LEN*NVH)/256, 256, 0, stream>>>(a_pre, b_pre, A_log, dt_bias, gv, bv);

  // 3) gate projection into reclaimed q_pre/k_pre region
  gemm_bt<<<dim3(VAL_DIM/64, S_LEN/64), 256, 0, stream>>>(x, Wg, gate, S_LEN, VAL_DIM, HID);

  // 4) sequential delta-rule scan (o -> reclaimed v_pre)
  scan_kernel<<<64, 256, 0, stream>>>(qn, kn, vcb, gv, bv, obuf);

  // 5) gated RMSNorm (og -> reclaimed vcb)
  norm_kernel<<<dim3(S_LEN, NVH), 128, 0, stream>>>(obuf, gate, w_norm, ogbuf);

  // 6) output projection
  gemm_bt<<<dim3(HID/64, S_LEN/64), 256, 0, stream>>>(ogbuf, Wo, out, S_LEN, HID, HID);
}